// Round 10
// baseline (834.484 us; speedup 1.0000x reference)
//
#include <hip/hip_runtime.h>
#include <hip/hip_bf16.h>
#include <stdint.h>

#define NTEST 4096
#define NTRAIN 16384
#define DIM 128
#define KEXP 128   // pure hi.hi bf16 (norms exact fp32)

typedef __attribute__((ext_vector_type(8))) short short8;
typedef __attribute__((ext_vector_type(16))) float float16v;

static __device__ __forceinline__ unsigned short f32_to_bf16_rne(float f) {
    union { float f; uint32_t u; } v; v.f = f;
    uint32_t u = v.u;
    uint32_t r = u + 0x7FFFu + ((u >> 16) & 1u);
    return (unsigned short)(r >> 16);
}

// ---- Kernel 1: per-column partial sums for std (coalesced) + zero out ----
__global__ void col_stats_partial(const float* __restrict__ train,
                                  float* __restrict__ psum, float* __restrict__ psumsq,
                                  float* __restrict__ out) {
    int b = blockIdx.x;       // 128 blocks x 128 rows each
    int t = threadIdx.x;      // 256
    if (b < 16) out[b * 256 + t] = 0.f;   // zero output (re-poisoned each call)
    int col = t & 127;
    int rh = t >> 7;          // 0/1
    float s = 0.f, ss = 0.f;
    int row0 = b * 128;
    for (int r = rh; r < 128; r += 2) {
        float x = train[(size_t)(row0 + r) * DIM + col];
        s += x; ss += x * x;
    }
    __shared__ float sh_s[256], sh_ss[256];
    sh_s[t] = s; sh_ss[t] = ss;
    __syncthreads();
    if (rh == 0) {
        psum[b * DIM + col]   = sh_s[col] + sh_s[col + 128];
        psumsq[b * DIM + col] = sh_ss[col] + sh_ss[col + 128];
    }
}

// ---- Kernel 2: bandwidth + Z scalars ----
__global__ void bandwidth_kernel(const float* __restrict__ psum, const float* __restrict__ psumsq,
                                 float* __restrict__ inv_bw, float* __restrict__ scalars) {
    int t = threadIdx.x;      // 256
    int c = t & 127;
    int h = t >> 7;
    float s = 0.f, ss = 0.f;
    for (int b = h * 64; b < h * 64 + 64; ++b) { s += psum[b * DIM + c]; ss += psumsq[b * DIM + c]; }
    __shared__ float S[256], SS[256], sh[128];
    S[t] = s; SS[t] = ss;
    __syncthreads();
    if (h == 0) {
        s = S[c] + S[c + 128]; ss = SS[c] + SS[c + 128];
        float n = (float)NTRAIN;
        float var = (ss - s * s / n) / (n - 1.0f);
        float sd = fmaxf(sqrtf(var), 0.01f);
        float bw = 1.06f * sd * expf(-logf(n) / (float)(4 + DIM));
        bw = fminf(bw, 0.49f);
        inv_bw[c] = 1.0f / bw;
        sh[c] = logf(bw);
    }
    __syncthreads();
    for (int off = 64; off > 0; off >>= 1) {
        if (t < off) sh[t] += sh[t + off];
        __syncthreads();
    }
    if (t == 0) {
        float Z = 0.5f * (float)DIM * logf(2.0f * 3.14159265358979323846f) + sh[0] + logf((float)NTRAIN);
        scalars[0] = -0.5f / Z;   // term = exp(scale*sq - 1)
    }
}

// ---- Kernel 3: train rows -> Bf in MFMA B-fragment order + S1-scaled norms ----
// Slice s5 = r>>5 (32 rows x 128 k = 4096 shorts). Within slice: chunk (k>>3)
// block of 256 shorts, row (r&31)*8, sub k&7. Wave slice for (tile j, wave w)
// = s5 = (grp*8+j)*4 + w; lane l reads addr = s5*4096 + l*8 + ks*512 (coalesced).
__global__ void expand_train(const float* __restrict__ train, const float* __restrict__ inv_bw,
                             const float* __restrict__ scalars,
                             unsigned short* __restrict__ Bf, float* __restrict__ rnp) {
    int t = threadIdx.x;
    int r = blockIdx.x * 2 + (t >> 7);    // 0..NTRAIN-1
    int k = t & 127;
    float x = train[(size_t)r * DIM + k] * inv_bw[k];
    int s5 = r >> 5;
    Bf[(size_t)s5 * 4096 + (k >> 3) * 256 + (r & 31) * 8 + (k & 7)] = f32_to_bf16_rne(x);
    float nv = x * x;   // exact fp32 norm
    #pragma unroll
    for (int off = 32; off > 0; off >>= 1) nv += __shfl_xor(nv, off, 64);
    __shared__ float sh[4];
    if ((t & 63) == 0) sh[t >> 6] = nv;
    __syncthreads();
    if (k == 0) {
        float S1 = scalars[0] * 1.44269504f;
        rnp[r] = S1 * (sh[(t >> 6)] + sh[(t >> 6) + 1]);   // pre-folded: S1*||r||^2
    }
}

// ---- Kernel 4: A in LDS, B double-buffered in REGISTERS (coalesced loads) ----
// No global_load_lds, no barriers in the j-loop: compiler tracks register deps
// with fine-grained vmcnt. term = exp2(S1*tn+C1) * exp2(K2*d + S1*rn).
__global__ __launch_bounds__(256, 3) void kde_main(
    const float* __restrict__ test, const unsigned short* __restrict__ Bf,
    const float* __restrict__ inv_bw, const float* __restrict__ rnp,
    const float* __restrict__ scalars, float* __restrict__ out) {

    __shared__ __align__(16) unsigned short As[64 * 128];   // 16 KB swizzled
    __shared__ float tn_lds[64];

    const int t = threadIdx.x;
    const int m0 = blockIdx.x * 64;      // 64 m-blocks
    const int grp = blockIdx.y;          // 16 n-groups x 8 tiles of 128
    const int wave = t >> 6;             // n-subtile owner (32 rows)
    const int lane = t & 63;
    const int col = lane & 31;           // operand row (m or n), C/D col
    const int half = lane >> 5;          // k-half; C/D row-group

    // B stream base: slice (j,wave) = ((grp*8+j)*4+wave) * 4096 shorts
    const unsigned short* pB = Bf + ((size_t)((grp * 8) * 4 + wave)) * 4096 + lane * 8;

    short8 Br0[8], Br1[8];
    float pn0, pn1;
    // prologue: issue tile-0 B loads + rnorm before A-build VALU work
    #pragma unroll
    for (int ks = 0; ks < 8; ++ks) Br0[ks] = *(const short8*)(pB + ks * 512);
    pn0 = rnp[grp * 1024 + wave * 32 + col];

    // ---- build A (bf16 of test*inv_bw) swizzled in LDS + exact tnorm ----
    {
        int p = t & 15;                       // 16B chunk within row
        float4 w0 = *(const float4*)(inv_bw + p * 8);
        float4 w1 = *(const float4*)(inv_bw + p * 8 + 4);
        #pragma unroll
        for (int rr = 0; rr < 4; ++rr) {
            int row = (t >> 4) + rr * 16;     // 0..63
            const float* src = test + (size_t)(m0 + row) * DIM + p * 8;
            float4 v0 = *(const float4*)(src);
            float4 v1 = *(const float4*)(src + 4);
            v0.x *= w0.x; v0.y *= w0.y; v0.z *= w0.z; v0.w *= w0.w;
            v1.x *= w1.x; v1.y *= w1.y; v1.z *= w1.z; v1.w *= w1.w;
            short8 hv;
            hv[0] = (short)f32_to_bf16_rne(v0.x); hv[1] = (short)f32_to_bf16_rne(v0.y);
            hv[2] = (short)f32_to_bf16_rne(v0.z); hv[3] = (short)f32_to_bf16_rne(v0.w);
            hv[4] = (short)f32_to_bf16_rne(v1.x); hv[5] = (short)f32_to_bf16_rne(v1.y);
            hv[6] = (short)f32_to_bf16_rne(v1.z); hv[7] = (short)f32_to_bf16_rne(v1.w);
            int pp = p ^ (row & 7);
            *(short8*)(As + row * 128 + pp * 8) = hv;
            float nv = v0.x*v0.x + v0.y*v0.y + v0.z*v0.z + v0.w*v0.w
                     + v1.x*v1.x + v1.y*v1.y + v1.z*v1.z + v1.w*v1.w;
            #pragma unroll
            for (int off = 1; off < 16; off <<= 1) nv += __shfl_xor(nv, off, 16);
            if ((t & 15) == 0) tn_lds[row] = nv;
        }
    }
    __syncthreads();   // the ONLY barrier: A + tnorm visible

    const float scale = scalars[0];
    const float L2E = 1.44269504f;
    const float S1 = scale * L2E;
    const float K2 = -2.0f * scale * L2E;
    const float C1 = -L2E;

    const int abase0 = (col) * 128,      arx0 = col & 7;          // tm=0 row
    const int abase1 = (32 + col) * 128, arx1 = (32 + col) & 7;   // tm=1 row

    float rs[2][16];
    #pragma unroll
    for (int tm = 0; tm < 2; ++tm)
        #pragma unroll
        for (int g = 0; g < 16; ++g) rs[tm][g] = 0.f;

    // compute one n-tile from register buffer BR with prescaled rnorm PN
#define COMPUTE_TILE(BR, PN)                                                          \
    {                                                                                 \
        float16v a0 = (float16v)(0.f), a1 = (float16v)(0.f);                          \
        _Pragma("unroll")                                                             \
        for (int ks = 0; ks < 8; ++ks) {                                              \
            short8 af0 = *(const short8*)(As + abase0 + (((ks * 2 + half) ^ arx0) << 3)); \
            short8 af1 = *(const short8*)(As + abase1 + (((ks * 2 + half) ^ arx1) << 3)); \
            a0 = __builtin_amdgcn_mfma_f32_32x32x16_bf16(af0, BR[ks], a0, 0, 0, 0);   \
            a1 = __builtin_amdgcn_mfma_f32_32x32x16_bf16(af1, BR[ks], a1, 0, 0, 0);   \
        }                                                                             \
        _Pragma("unroll")                                                             \
        for (int g = 0; g < 16; ++g) rs[0][g] += exp2f(fmaf(K2, a0[g], PN));          \
        _Pragma("unroll")                                                             \
        for (int g = 0; g < 16; ++g) rs[1][g] += exp2f(fmaf(K2, a1[g], PN));          \
    }

    // ---- 8 n-tiles, barrier-free, compile-time register double-buffer ----
    #pragma unroll
    for (int j = 0; j < 8; j += 2) {
        {   // prefetch tile j+1 into Br1
            const unsigned short* p1 = pB + (size_t)(j + 1) * 16384;
            #pragma unroll
            for (int ks = 0; ks < 8; ++ks) Br1[ks] = *(const short8*)(p1 + ks * 512);
            pn1 = rnp[(grp * 8 + j + 1) * 128 + wave * 32 + col];
        }
        COMPUTE_TILE(Br0, pn0);
        if (j + 2 < 8) {   // prefetch tile j+2 into Br0
            const unsigned short* p2 = pB + (size_t)(j + 2) * 16384;
            #pragma unroll
            for (int ks = 0; ks < 8; ++ks) Br0[ks] = *(const short8*)(p2 + ks * 512);
            pn0 = rnp[(grp * 8 + j + 2) * 128 + wave * 32 + col];
        }
        COMPUTE_TILE(Br1, pn1);
    }
#undef COMPUTE_TILE

    // ---- final: fold tn factor, reduce across 32 cols, one atomic each ----
    #pragma unroll
    for (int tm = 0; tm < 2; ++tm) {
        #pragma unroll
        for (int g = 0; g < 16; ++g) {
            int rowi = tm * 32 + (g & 3) + 8 * (g >> 2) + 4 * half;
            float v = rs[tm][g] * exp2f(fmaf(S1, tn_lds[rowi], C1));
            #pragma unroll
            for (int off = 1; off < 32; off <<= 1)
                v += __shfl_xor(v, off, 64);   // offs 1..16: stays within 32-lane half
            if (col == 0) atomicAdd(&out[m0 + rowi], v);
        }
    }
}

extern "C" void kernel_launch(void* const* d_in, const int* in_sizes, int n_in,
                              void* d_out, int out_size, void* d_ws, size_t ws_size,
                              hipStream_t stream) {
    const float* test  = (const float*)d_in[0];
    const float* train = (const float*)d_in[1];
    float* out = (float*)d_out;

    char* ws = (char*)d_ws;
    unsigned short* Bf = (unsigned short*)ws;            // 16384*128*2 = 4,194,304 B
    float* fws    = (float*)(ws + 4194304);
    float* rnp    = fws;                 // 16384 (S1-prescaled norms)
    float* psum   = rnp + NTRAIN;        // 16384
    float* psumsq = psum + 16384;        // 16384
    float* inv_bw = psumsq + 16384;      // 128
    float* scalars = inv_bw + 128;       // 8

    hipLaunchKernelGGL(col_stats_partial, dim3(128), dim3(256), 0, stream, train, psum, psumsq, out);
    hipLaunchKernelGGL(bandwidth_kernel, dim3(1), dim3(256), 0, stream, psum, psumsq, inv_bw, scalars);
    hipLaunchKernelGGL(expand_train, dim3(NTRAIN / 2), dim3(256), 0, stream,
                       train, inv_bw, scalars, Bf, rnp);
    hipLaunchKernelGGL(kde_main, dim3(NTEST / 64, 16), dim3(256), 0, stream,
                       test, Bf, inv_bw, rnp, scalars, out);
}

// Round 11
// 145.490 us; speedup vs baseline: 5.7357x; 5.7357x over previous
//
#include <hip/hip_runtime.h>
#include <hip/hip_bf16.h>
#include <stdint.h>

#define NTEST 4096
#define NTRAIN 16384
#define DIM 128
#define KEXP 128   // pure hi.hi bf16 (norms exact fp32)

typedef __attribute__((ext_vector_type(8))) short short8;
typedef __attribute__((ext_vector_type(16))) float float16v;

static __device__ __forceinline__ unsigned short f32_to_bf16_rne(float f) {
    union { float f; uint32_t u; } v; v.f = f;
    uint32_t u = v.u;
    uint32_t r = u + 0x7FFFu + ((u >> 16) & 1u);
    return (unsigned short)(r >> 16);
}

// ---- Kernel 1: per-column partial sums for std (coalesced) + zero out ----
__global__ void col_stats_partial(const float* __restrict__ train,
                                  float* __restrict__ psum, float* __restrict__ psumsq,
                                  float* __restrict__ out) {
    int b = blockIdx.x;       // 128 blocks x 128 rows each
    int t = threadIdx.x;      // 256
    if (b < 16) out[b * 256 + t] = 0.f;   // zero output (re-poisoned each call)
    int col = t & 127;
    int rh = t >> 7;          // 0/1
    float s = 0.f, ss = 0.f;
    int row0 = b * 128;
    for (int r = rh; r < 128; r += 2) {
        float x = train[(size_t)(row0 + r) * DIM + col];
        s += x; ss += x * x;
    }
    __shared__ float sh_s[256], sh_ss[256];
    sh_s[t] = s; sh_ss[t] = ss;
    __syncthreads();
    if (rh == 0) {
        psum[b * DIM + col]   = sh_s[col] + sh_s[col + 128];
        psumsq[b * DIM + col] = sh_ss[col] + sh_ss[col + 128];
    }
}

// ---- Kernel 2: bandwidth + Z scalars ----
__global__ void bandwidth_kernel(const float* __restrict__ psum, const float* __restrict__ psumsq,
                                 float* __restrict__ inv_bw, float* __restrict__ scalars) {
    int t = threadIdx.x;      // 256
    int c = t & 127;
    int h = t >> 7;
    float s = 0.f, ss = 0.f;
    for (int b = h * 64; b < h * 64 + 64; ++b) { s += psum[b * DIM + c]; ss += psumsq[b * DIM + c]; }
    __shared__ float S[256], SS[256], sh[128];
    S[t] = s; SS[t] = ss;
    __syncthreads();
    if (h == 0) {
        s = S[c] + S[c + 128]; ss = SS[c] + SS[c + 128];
        float n = (float)NTRAIN;
        float var = (ss - s * s / n) / (n - 1.0f);
        float sd = fmaxf(sqrtf(var), 0.01f);
        float bw = 1.06f * sd * expf(-logf(n) / (float)(4 + DIM));
        bw = fminf(bw, 0.49f);
        inv_bw[c] = 1.0f / bw;
        sh[c] = logf(bw);
    }
    __syncthreads();
    for (int off = 64; off > 0; off >>= 1) {
        if (t < off) sh[t] += sh[t + off];
        __syncthreads();
    }
    if (t == 0) {
        float Z = 0.5f * (float)DIM * logf(2.0f * 3.14159265358979323846f) + sh[0] + logf((float)NTRAIN);
        scalars[0] = -0.5f / Z;   // term = exp(scale*sq - 1)
    }
}

// ---- Kernel 3: train rows -> Bf in MFMA B-fragment order + S1-scaled norms ----
// Slice s5 = r>>5 (32 rows x 128 k = 4096 shorts). Within slice: chunk (k>>3)
// block of 256 shorts, row (r&31)*8, sub k&7. Wave slice for (tile j, wave w)
// = s5 = (grp*8+j)*4 + w; lane l reads addr = s5*4096 + l*8 + ks*512 (coalesced).
__global__ void expand_train(const float* __restrict__ train, const float* __restrict__ inv_bw,
                             const float* __restrict__ scalars,
                             unsigned short* __restrict__ Bf, float* __restrict__ rnp) {
    int t = threadIdx.x;
    int r = blockIdx.x * 2 + (t >> 7);    // 0..NTRAIN-1
    int k = t & 127;
    float x = train[(size_t)r * DIM + k] * inv_bw[k];
    int s5 = r >> 5;
    Bf[(size_t)s5 * 4096 + (k >> 3) * 256 + (r & 31) * 8 + (k & 7)] = f32_to_bf16_rne(x);
    float nv = x * x;   // exact fp32 norm
    #pragma unroll
    for (int off = 32; off > 0; off >>= 1) nv += __shfl_xor(nv, off, 64);
    __shared__ float sh[4];
    if ((t & 63) == 0) sh[t >> 6] = nv;
    __syncthreads();
    if (k == 0) {
        float S1 = scalars[0] * 1.44269504f;
        rnp[r] = S1 * (sh[(t >> 6)] + sh[(t >> 6) + 1]);   // pre-folded: S1*||r||^2
    }
}

// ---- Kernel 4: A in LDS, B in registers, half-tile pipelined, no spill ----
// j-loop is a REAL loop (unroll 1) so B-buffer liveness is one iteration.
// B0/B1 = 4 chunks each (16+16 VGPRs). term = exp2(S1*tn+C1)*exp2(K2*d+S1*rn).
__global__ __launch_bounds__(256, 3) void kde_main(
    const float* __restrict__ test, const unsigned short* __restrict__ Bf,
    const float* __restrict__ inv_bw, const float* __restrict__ rnp,
    const float* __restrict__ scalars, float* __restrict__ out) {

    __shared__ __align__(16) unsigned short As[64 * 128];   // 16 KB swizzled
    __shared__ float tn_lds[64];

    const int t = threadIdx.x;
    const int m0 = blockIdx.x * 64;      // 64 m-blocks
    const int grp = blockIdx.y;          // 16 n-groups x 8 tiles of 128
    const int wave = t >> 6;             // n-subtile owner (32 rows)
    const int lane = t & 63;
    const int col = lane & 31;           // operand row (m or n), C/D col
    const int half = lane >> 5;          // k-half; C/D row-group

    // B stream base: slice (j,wave) = ((grp*8+j)*4+wave) * 4096 shorts
    const unsigned short* pB = Bf + ((size_t)((grp * 8) * 4 + wave)) * 4096 + lane * 8;

    short8 B0[4], B1[4];
    float pn0;
    // prologue: issue tile-0 B loads + rnorm before A-build VALU work
    #pragma unroll
    for (int ks = 0; ks < 4; ++ks) B0[ks] = *(const short8*)(pB + ks * 512);
    #pragma unroll
    for (int ks = 0; ks < 4; ++ks) B1[ks] = *(const short8*)(pB + (ks + 4) * 512);
    pn0 = rnp[grp * 1024 + wave * 32 + col];

    // ---- build A (bf16 of test*inv_bw) swizzled in LDS + exact tnorm ----
    {
        int p = t & 15;                       // 16B chunk within row
        float4 w0 = *(const float4*)(inv_bw + p * 8);
        float4 w1 = *(const float4*)(inv_bw + p * 8 + 4);
        #pragma unroll
        for (int rr = 0; rr < 4; ++rr) {
            int row = (t >> 4) + rr * 16;     // 0..63
            const float* src = test + (size_t)(m0 + row) * DIM + p * 8;
            float4 v0 = *(const float4*)(src);
            float4 v1 = *(const float4*)(src + 4);
            v0.x *= w0.x; v0.y *= w0.y; v0.z *= w0.z; v0.w *= w0.w;
            v1.x *= w1.x; v1.y *= w1.y; v1.z *= w1.z; v1.w *= w1.w;
            short8 hv;
            hv[0] = (short)f32_to_bf16_rne(v0.x); hv[1] = (short)f32_to_bf16_rne(v0.y);
            hv[2] = (short)f32_to_bf16_rne(v0.z); hv[3] = (short)f32_to_bf16_rne(v0.w);
            hv[4] = (short)f32_to_bf16_rne(v1.x); hv[5] = (short)f32_to_bf16_rne(v1.y);
            hv[6] = (short)f32_to_bf16_rne(v1.z); hv[7] = (short)f32_to_bf16_rne(v1.w);
            int pp = p ^ (row & 7);
            *(short8*)(As + row * 128 + pp * 8) = hv;
            float nv = v0.x*v0.x + v0.y*v0.y + v0.z*v0.z + v0.w*v0.w
                     + v1.x*v1.x + v1.y*v1.y + v1.z*v1.z + v1.w*v1.w;
            #pragma unroll
            for (int off = 1; off < 16; off <<= 1) nv += __shfl_xor(nv, off, 16);
            if ((t & 15) == 0) tn_lds[row] = nv;
        }
    }
    __syncthreads();   // the ONLY barrier: A + tnorm visible

    const float scale = scalars[0];
    const float L2E = 1.44269504f;
    const float S1 = scale * L2E;
    const float K2 = -2.0f * scale * L2E;
    const float C1 = -L2E;

    const int abase0 = (col) * 128,      arx0 = col & 7;          // tm=0 row
    const int abase1 = (32 + col) * 128, arx1 = (32 + col) & 7;   // tm=1 row

    float rs[2][16];
    #pragma unroll
    for (int tm = 0; tm < 2; ++tm)
        #pragma unroll
        for (int g = 0; g < 16; ++g) rs[tm][g] = 0.f;

    // ---- 8 n-tiles, barrier-free, half-tile register pipeline ----
    #pragma unroll 1
    for (int j = 0; j < 8; ++j) {
        float pnc = pn0;
        float16v a0 = (float16v)(0.f), a1 = (float16v)(0.f);
        // compute half 0 (ks 0..3) from B0
        #pragma unroll
        for (int ks = 0; ks < 4; ++ks) {
            short8 af0 = *(const short8*)(As + abase0 + (((ks * 2 + half) ^ arx0) << 3));
            short8 af1 = *(const short8*)(As + abase1 + (((ks * 2 + half) ^ arx1) << 3));
            a0 = __builtin_amdgcn_mfma_f32_32x32x16_bf16(af0, B0[ks], a0, 0, 0, 0);
            a1 = __builtin_amdgcn_mfma_f32_32x32x16_bf16(af1, B0[ks], a1, 0, 0, 0);
        }
        // prefetch half 0 of tile j+1 into B0 (used after h1-compute + epilogue)
        if (j < 7) {
            const unsigned short* pN = pB + (size_t)(j + 1) * 16384;
            #pragma unroll
            for (int ks = 0; ks < 4; ++ks) B0[ks] = *(const short8*)(pN + ks * 512);
        }
        // compute half 1 (ks 4..7) from B1
        #pragma unroll
        for (int ks = 4; ks < 8; ++ks) {
            short8 af0 = *(const short8*)(As + abase0 + (((ks * 2 + half) ^ arx0) << 3));
            short8 af1 = *(const short8*)(As + abase1 + (((ks * 2 + half) ^ arx1) << 3));
            a0 = __builtin_amdgcn_mfma_f32_32x32x16_bf16(af0, B1[ks - 4], a0, 0, 0, 0);
            a1 = __builtin_amdgcn_mfma_f32_32x32x16_bf16(af1, B1[ks - 4], a1, 0, 0, 0);
        }
        // prefetch half 1 of tile j+1 into B1 + next rnorm
        if (j < 7) {
            const unsigned short* pN = pB + (size_t)(j + 1) * 16384;
            #pragma unroll
            for (int ks = 0; ks < 4; ++ks) B1[ks] = *(const short8*)(pN + (ks + 4) * 512);
            pn0 = rnp[(grp * 8 + j + 1) * 128 + wave * 32 + col];
        }
        // epilogue: folded exp2 into register rowsums
        #pragma unroll
        for (int g = 0; g < 16; ++g) rs[0][g] += exp2f(fmaf(K2, a0[g], pnc));
        #pragma unroll
        for (int g = 0; g < 16; ++g) rs[1][g] += exp2f(fmaf(K2, a1[g], pnc));
    }

    // ---- final: fold tn factor, reduce across 32 cols, one atomic each ----
    #pragma unroll
    for (int tm = 0; tm < 2; ++tm) {
        #pragma unroll
        for (int g = 0; g < 16; ++g) {
            int rowi = tm * 32 + (g & 3) + 8 * (g >> 2) + 4 * half;
            float v = rs[tm][g] * exp2f(fmaf(S1, tn_lds[rowi], C1));
            #pragma unroll
            for (int off = 1; off < 32; off <<= 1)
                v += __shfl_xor(v, off, 64);   // offs 1..16: stays within 32-lane half
            if (col == 0) atomicAdd(&out[m0 + rowi], v);
        }
    }
}

extern "C" void kernel_launch(void* const* d_in, const int* in_sizes, int n_in,
                              void* d_out, int out_size, void* d_ws, size_t ws_size,
                              hipStream_t stream) {
    const float* test  = (const float*)d_in[0];
    const float* train = (const float*)d_in[1];
    float* out = (float*)d_out;

    char* ws = (char*)d_ws;
    unsigned short* Bf = (unsigned short*)ws;            // 16384*128*2 = 4,194,304 B
    float* fws    = (float*)(ws + 4194304);
    float* rnp    = fws;                 // 16384 (S1-prescaled norms)
    float* psum   = rnp + NTRAIN;        // 16384
    float* psumsq = psum + 16384;        // 16384
    float* inv_bw = psumsq + 16384;      // 128
    float* scalars = inv_bw + 128;       // 8

    hipLaunchKernelGGL(col_stats_partial, dim3(128), dim3(256), 0, stream, train, psum, psumsq, out);
    hipLaunchKernelGGL(bandwidth_kernel, dim3(1), dim3(256), 0, stream, psum, psumsq, inv_bw, scalars);
    hipLaunchKernelGGL(expand_train, dim3(NTRAIN / 2), dim3(256), 0, stream,
                       train, inv_bw, scalars, Bf, rnp);
    hipLaunchKernelGGL(kde_main, dim3(NTEST / 64, 16), dim3(256), 0, stream,
                       test, Bf, inv_bw, rnp, scalars, out);
}